// Round 1
// baseline (581.934 us; speedup 1.0000x reference)
//
#include <hip/hip_runtime.h>
#include <stdint.h>

typedef __attribute__((ext_vector_type(8))) short bf16x8;
typedef __attribute__((ext_vector_type(4))) float f32x4;

#define D_IN  4096
#define D_OUT 4096
#define KC 512   // per-component input dim
#define NC 512   // per-component output dim
#define BM 128
#define BN 128
#define BK 64
#define NSTEP (D_IN / BK)   // 64

// SIGN_TABLE[i][j], row-major
__constant__ float c_sign[64] = {
 +1,-1,-1,-1,-1,-1,-1,-1,
 +1,+1,+1,-1,+1,-1,-1,+1,
 +1,-1,+1,+1,+1,+1,-1,-1,
 +1,+1,-1,+1,+1,-1,+1,-1,
 +1,-1,-1,-1,+1,+1,+1,+1,
 +1,+1,-1,+1,-1,+1,-1,+1,
 +1,+1,+1,-1,-1,+1,+1,-1,
 +1,-1,+1,+1,-1,-1,+1,+1,
};

__device__ inline unsigned int pack2bf16(float a, float b) {
    // round-to-nearest-even bf16 pack (inputs are finite; no NaN path needed)
    unsigned int ua = __builtin_bit_cast(unsigned int, a);
    unsigned int ub = __builtin_bit_cast(unsigned int, b);
    ua = (ua + 0x7FFFu + ((ua >> 16) & 1u)) >> 16;
    ub = (ub + 0x7FFFu + ((ub >> 16) & 1u)) >> 16;
    return ua | (ub << 16);
}

__global__ __launch_bounds__(256)
void octo_gemm(const float* __restrict__ X, const float* __restrict__ W,
               float* __restrict__ Y, int M)
{
    // bf16 tiles, XOR-swizzled in 16B chunks within each 128B row:
    // element (r, kcol) lives at byte r*128 + ((chunk ^ (r&7))<<4) + (byte&15),
    // chunk = (kcol*2)>>4. Breaks the 128B-row-stride full-column bank conflict.
    __shared__ __align__(16) unsigned short As[BM * BK];
    __shared__ __align__(16) unsigned short Bs[BN * BK];

    const int tid  = threadIdx.x;
    const int lane = tid & 63;
    const int wave = tid >> 6;
    const int wr   = wave >> 1;      // 2x2 wave grid, each wave owns 64x64
    const int wc   = wave & 1;

    const int nbn = D_OUT / BN;                 // 32
    const int nwg = (M / BM) * nbn;             // 2048
    int bid = blockIdx.x;
    int wg  = bid;
    if ((nwg & 7) == 0) {                       // bijective XCD swizzle
        int cpx = nwg >> 3;
        wg = (bid & 7) * cpx + (bid >> 3);
    }
    const int bm = wg / nbn, bn = wg % nbn;
    const int row0  = bm * BM;                  // output row base
    const int col0  = bn * BN;                  // output col base
    const int icomp = col0 >> 9;                // octonion output component i
    const int noff  = col0 & (NC - 1);          // row offset inside W[.]

    // staging: 16 lanes per row, 16 rows per pass, 8 passes
    const int srow = tid >> 4;                  // 0..15
    const int scol = (tid & 15) << 2;           // float4 column: 0,4,...,60

    f32x4 acc[4][4];
    #pragma unroll
    for (int m = 0; m < 4; ++m)
        #pragma unroll
        for (int n = 0; n < 4; ++n)
            acc[m][n] = (f32x4){0.f, 0.f, 0.f, 0.f};

    char* AsB = (char*)As;
    char* BsB = (char*)Bs;

    // precomputed swizzled staging byte offset (same for A and B tiles)
    const int byteC = scol << 1;                               // 0..120, mult of 8

    for (int step = 0; step < NSTEP; ++step) {
        const int k0 = step * BK;
        const int j  = k0 >> 9;                 // input component j (uniform/blk)
        const int kc = k0 & (KC - 1);
        const float sgn = c_sign[icomp * 8 + j];
        const int   w   = icomp ^ j;            // WEIGHT_IDX[i][j] == i^j
        const float* Wp = W + ((w * NC + noff) * KC + kc);
        const float* Xp = X + (row0 * D_IN + k0);

        __syncthreads();   // previous tile's reads complete
        #pragma unroll
        for (int p = 0; p < 8; ++p) {
            const int r  = p * 16 + srow;
            const int sb = r * 128 + ((((byteC >> 4) ^ (r & 7)) << 4)) + (byteC & 8);
            // A panel: X[row0+r][k0+scol .. +3]
            const float4 va = *(const float4*)(&Xp[r * D_IN + scol]);
            *(uint2*)(AsB + sb) = make_uint2(pack2bf16(va.x, va.y),
                                             pack2bf16(va.z, va.w));
            // B panel: sign * W[i^j][noff+r][kc+scol .. +3]
            const float4 vb = *(const float4*)(&Wp[r * KC + scol]);
            *(uint2*)(BsB + sb) = make_uint2(pack2bf16(vb.x * sgn, vb.y * sgn),
                                             pack2bf16(vb.z * sgn, vb.w * sgn));
        }
        __syncthreads();

        #pragma unroll
        for (int kk = 0; kk < 2; ++kk) {
            bf16x8 af[4], bf[4];
            #pragma unroll
            for (int m = 0; m < 4; ++m) {
                const int r = wr * 64 + m * 16 + (lane & 15);
                const int chunk = (kk * 4 + (lane >> 4)) ^ (r & 7);
                af[m] = *(const bf16x8*)(AsB + r * 128 + (chunk << 4));
            }
            #pragma unroll
            for (int n = 0; n < 4; ++n) {
                const int r = wc * 64 + n * 16 + (lane & 15);
                const int chunk = (kk * 4 + (lane >> 4)) ^ (r & 7);
                bf[n] = *(const bf16x8*)(BsB + r * 128 + (chunk << 4));
            }
            #pragma unroll
            for (int m = 0; m < 4; ++m)
                #pragma unroll
                for (int n = 0; n < 4; ++n)
                    acc[m][n] = __builtin_amdgcn_mfma_f32_16x16x32_bf16(
                        af[m], bf[n], acc[m][n], 0, 0, 0);
        }
    }

    // epilogue: C/D layout col=lane&15, row=(lane>>4)*4+reg  [m89/m91]
    const int rl = (lane >> 4) << 2;
    const int cl = lane & 15;
    #pragma unroll
    for (int m = 0; m < 4; ++m) {
        const int rg = row0 + wr * 64 + m * 16 + rl;
        #pragma unroll
        for (int n = 0; n < 4; ++n) {
            const int cg = col0 + wc * 64 + n * 16 + cl;
            #pragma unroll
            for (int q = 0; q < 4; ++q)
                Y[(rg + q) * D_OUT + cg] = acc[m][n][q];
        }
    }
}

extern "C" void kernel_launch(void* const* d_in, const int* in_sizes, int n_in,
                              void* d_out, int out_size, void* d_ws, size_t ws_size,
                              hipStream_t stream) {
    const float* X = (const float*)d_in[0];   // [B*T, 4096] fp32
    const float* W = (const float*)d_in[1];   // [8, 512, 512] fp32
    float* Y = (float*)d_out;                 // [B*T, 4096] fp32
    const int M = in_sizes[0] / D_IN;         // 8192
    const int nwg = (M / BM) * (D_OUT / BN);  // 2048
    hipLaunchKernelGGL(octo_gemm, dim3(nwg), dim3(256), 0, stream, X, W, Y, M);
}

// Round 2
// 314.706 us; speedup vs baseline: 1.8491x; 1.8491x over previous
//
#include <hip/hip_runtime.h>
#include <stdint.h>

typedef __attribute__((ext_vector_type(8))) short bf16x8;
typedef __attribute__((ext_vector_type(4))) float f32x4;

#define D_IN  4096
#define D_OUT 4096
#define KC 512   // per-component input dim
#define NC 512   // per-component output dim
#define BM 128
#define BN 128
#define BK 64
#define NSTEP (D_IN / BK)   // 64

// SIGN_TABLE[i][j], row-major
__constant__ float c_sign[64] = {
 +1,-1,-1,-1,-1,-1,-1,-1,
 +1,+1,+1,-1,+1,-1,-1,+1,
 +1,-1,+1,+1,+1,+1,-1,-1,
 +1,+1,-1,+1,+1,-1,+1,-1,
 +1,-1,-1,-1,+1,+1,+1,+1,
 +1,+1,-1,+1,-1,+1,-1,+1,
 +1,+1,+1,-1,-1,+1,+1,-1,
 +1,-1,+1,+1,-1,-1,+1,+1,
};

__device__ inline unsigned int pack2bf16(float a, float b) {
    // round-to-nearest-even bf16 pack (inputs finite; no NaN path needed)
    unsigned int ua = __builtin_bit_cast(unsigned int, a);
    unsigned int ub = __builtin_bit_cast(unsigned int, b);
    ua = (ua + 0x7FFFu + ((ua >> 16) & 1u)) >> 16;
    ub = (ub + 0x7FFFu + ((ub >> 16) & 1u)) >> 16;
    return ua | (ub << 16);
}

typedef __attribute__((address_space(1))) const unsigned int gas_u32;
typedef __attribute__((address_space(3))) unsigned int las_u32;
#define ASYNC16(g, l) __builtin_amdgcn_global_load_lds((gas_u32*)(g), (las_u32*)(l), 16, 0, 0)

// ---------- pre-conversion kernels ----------

// X fp32 -> bf16, 8 elems/thread
__global__ __launch_bounds__(256)
void conv_x(const float* __restrict__ in, unsigned short* __restrict__ out, int n8) {
    int i = blockIdx.x * blockDim.x + threadIdx.x;
    if (i >= n8) return;
    const float4 a = ((const float4*)in)[(size_t)i * 2];
    const float4 b = ((const float4*)in)[(size_t)i * 2 + 1];
    uint4 o;
    o.x = pack2bf16(a.x, a.y); o.y = pack2bf16(a.z, a.w);
    o.z = pack2bf16(b.x, b.y); o.w = pack2bf16(b.z, b.w);
    ((uint4*)out)[i] = o;
}

// Wbig[i*512+n][j*512+k] = sign[i][j] * W[i^j][n][k], fp32 -> bf16
__global__ __launch_bounds__(256)
void conv_w(const float* __restrict__ W, unsigned short* __restrict__ out) {
    int gid = blockIdx.x * blockDim.x + threadIdx.x;   // 0 .. 4096*512-1
    int row = gid >> 9;            // 0..4095 : i*512 + n
    int c8  = gid & 511;           // col = c8*8
    int i = row >> 9, n = row & 511;
    int j = c8 >> 6;
    int k = (c8 & 63) << 3;
    float sgn = c_sign[i * 8 + j];
    const float* src = W + ((((i ^ j) * NC + n) * KC) + k);
    float4 a = *(const float4*)(src);
    float4 b = *(const float4*)(src + 4);
    uint4 o;
    o.x = pack2bf16(a.x * sgn, a.y * sgn); o.y = pack2bf16(a.z * sgn, a.w * sgn);
    o.z = pack2bf16(b.x * sgn, b.y * sgn); o.w = pack2bf16(b.z * sgn, b.w * sgn);
    ((uint4*)out)[gid] = o;
}

// ---------- bf16 GEMM: Y[M,4096] = Xb @ Wbig^T, m97 structure ----------

__global__ __launch_bounds__(256)
void octo_gemm_bf16(const unsigned short* __restrict__ Xb,
                    const unsigned short* __restrict__ Wb,
                    float* __restrict__ Y, int M)
{
    // LDS layout: linear dest for global_load_lds; logical element (r, k) of
    // the 128x64 bf16 tile lives at byte r*128 + ((chunk ^ (r&7))<<4) + low,
    // achieved by inverse-swizzling the GLOBAL source chunk (rule #21).
    __shared__ __align__(16) unsigned short As[BM * BK];
    __shared__ __align__(16) unsigned short Bs[BN * BK];

    const int tid  = threadIdx.x;
    const int lane = tid & 63;
    const int wave = tid >> 6;
    const int wr   = wave >> 1;      // 2x2 wave grid, each wave owns 64x64
    const int wc   = wave & 1;

    const int nbn = D_OUT / BN;                 // 32
    int bid = blockIdx.x;
    int cpx = (M / BM) * nbn >> 3;              // nwg/8 (nwg % 8 == 0)
    int wg  = (bid & 7) * cpx + (bid >> 3);     // bijective XCD swizzle
    const int bm = wg / nbn, bn = wg % nbn;
    const int row0 = bm * BM;
    const int col0 = bn * BN;

    // staging coords: 8 chunks (16B) per 128B row; 32 rows per issue, 4 issues
    const int sr = tid >> 3;                    // 0..31
    const int sc = tid & 7;                     // chunk 0..7

    f32x4 acc[4][4];
    #pragma unroll
    for (int m = 0; m < 4; ++m)
        #pragma unroll
        for (int n = 0; n < 4; ++n)
            acc[m][n] = (f32x4){0.f, 0.f, 0.f, 0.f};

    const char* AsB = (const char*)As;
    const char* BsB = (const char*)Bs;

    for (int step = 0; step < NSTEP; ++step) {
        const int k0 = step * BK;
        if (step) __syncthreads();              // prev tile's reads complete
        #pragma unroll
        for (int p = 0; p < 4; ++p) {
            const int r  = p * 32 + sr;
            const int cs = sc ^ (r & 7);        // inverse-swizzled source chunk
            ASYNC16(Xb + (size_t)(row0 + r) * D_IN + k0 + cs * 8,
                    As + p * 2048 + tid * 8);
            ASYNC16(Wb + (size_t)(col0 + r) * D_IN + k0 + cs * 8,
                    Bs + p * 2048 + tid * 8);
        }
        __syncthreads();                        // drains vmcnt -> tiles ready

        #pragma unroll
        for (int kk = 0; kk < 2; ++kk) {
            bf16x8 af[4], bf[4];
            #pragma unroll
            for (int m = 0; m < 4; ++m) {
                const int r = wr * 64 + m * 16 + (lane & 15);
                const int chunk = (kk * 4 + (lane >> 4)) ^ (r & 7);
                af[m] = *(const bf16x8*)(AsB + r * 128 + (chunk << 4));
            }
            #pragma unroll
            for (int n = 0; n < 4; ++n) {
                const int r = wc * 64 + n * 16 + (lane & 15);
                const int chunk = (kk * 4 + (lane >> 4)) ^ (r & 7);
                bf[n] = *(const bf16x8*)(BsB + r * 128 + (chunk << 4));
            }
            #pragma unroll
            for (int m = 0; m < 4; ++m)
                #pragma unroll
                for (int n = 0; n < 4; ++n)
                    acc[m][n] = __builtin_amdgcn_mfma_f32_16x16x32_bf16(
                        af[m], bf[n], acc[m][n], 0, 0, 0);
        }
    }

    // epilogue: C/D layout col=lane&15, row=(lane>>4)*4+reg  [m89/m91]
    const int rl = (lane >> 4) << 2;
    const int cl = lane & 15;
    #pragma unroll
    for (int m = 0; m < 4; ++m) {
        const int rg = row0 + wr * 64 + m * 16 + rl;
        #pragma unroll
        for (int n = 0; n < 4; ++n) {
            const int cg = col0 + wc * 64 + n * 16 + cl;
            #pragma unroll
            for (int q = 0; q < 4; ++q)
                Y[(size_t)(rg + q) * D_OUT + cg] = acc[m][n][q];
        }
    }
}

// ---------- fallback: round-1 fused kernel (no workspace) ----------

__global__ __launch_bounds__(256)
void octo_gemm_f32(const float* __restrict__ X, const float* __restrict__ W,
                   float* __restrict__ Y, int M)
{
    __shared__ __align__(16) unsigned short As[BM * BK];
    __shared__ __align__(16) unsigned short Bs[BN * BK];

    const int tid  = threadIdx.x;
    const int lane = tid & 63;
    const int wave = tid >> 6;
    const int wr   = wave >> 1;
    const int wc   = wave & 1;

    const int nbn = D_OUT / BN;
    const int nwg = (M / BM) * nbn;
    int bid = blockIdx.x;
    int wg  = bid;
    if ((nwg & 7) == 0) {
        int cpx = nwg >> 3;
        wg = (bid & 7) * cpx + (bid >> 3);
    }
    const int bm = wg / nbn, bn = wg % nbn;
    const int row0  = bm * BM;
    const int col0  = bn * BN;
    const int icomp = col0 >> 9;
    const int noff  = col0 & (NC - 1);

    const int srow = tid >> 4;
    const int scol = (tid & 15) << 2;

    f32x4 acc[4][4];
    #pragma unroll
    for (int m = 0; m < 4; ++m)
        #pragma unroll
        for (int n = 0; n < 4; ++n)
            acc[m][n] = (f32x4){0.f, 0.f, 0.f, 0.f};

    char* AsB = (char*)As;
    char* BsB = (char*)Bs;
    const int byteC = scol << 1;

    for (int step = 0; step < NSTEP; ++step) {
        const int k0 = step * BK;
        const int j  = k0 >> 9;
        const int kc = k0 & (KC - 1);
        const float sgn = c_sign[icomp * 8 + j];
        const int   w   = icomp ^ j;
        const float* Wp = W + (((size_t)w * NC + noff) * KC + kc);
        const float* Xp = X + ((size_t)row0 * D_IN + k0);

        __syncthreads();
        #pragma unroll
        for (int p = 0; p < 8; ++p) {
            const int r  = p * 16 + srow;
            const int sb = r * 128 + ((((byteC >> 4) ^ (r & 7)) << 4)) + (byteC & 8);
            const float4 va = *(const float4*)(&Xp[(size_t)r * D_IN + scol]);
            *(uint2*)(AsB + sb) = make_uint2(pack2bf16(va.x, va.y),
                                             pack2bf16(va.z, va.w));
            const float4 vb = *(const float4*)(&Wp[(size_t)r * KC + scol]);
            *(uint2*)(BsB + sb) = make_uint2(pack2bf16(vb.x * sgn, vb.y * sgn),
                                             pack2bf16(vb.z * sgn, vb.w * sgn));
        }
        __syncthreads();

        #pragma unroll
        for (int kk = 0; kk < 2; ++kk) {
            bf16x8 af[4], bf[4];
            #pragma unroll
            for (int m = 0; m < 4; ++m) {
                const int r = wr * 64 + m * 16 + (lane & 15);
                const int chunk = (kk * 4 + (lane >> 4)) ^ (r & 7);
                af[m] = *(const bf16x8*)(AsB + r * 128 + (chunk << 4));
            }
            #pragma unroll
            for (int n = 0; n < 4; ++n) {
                const int r = wc * 64 + n * 16 + (lane & 15);
                const int chunk = (kk * 4 + (lane >> 4)) ^ (r & 7);
                bf[n] = *(const bf16x8*)(BsB + r * 128 + (chunk << 4));
            }
            #pragma unroll
            for (int m = 0; m < 4; ++m)
                #pragma unroll
                for (int n = 0; n < 4; ++n)
                    acc[m][n] = __builtin_amdgcn_mfma_f32_16x16x32_bf16(
                        af[m], bf[n], acc[m][n], 0, 0, 0);
        }
    }

    const int rl = (lane >> 4) << 2;
    const int cl = lane & 15;
    #pragma unroll
    for (int m = 0; m < 4; ++m) {
        const int rg = row0 + wr * 64 + m * 16 + rl;
        #pragma unroll
        for (int n = 0; n < 4; ++n) {
            const int cg = col0 + wc * 64 + n * 16 + cl;
            #pragma unroll
            for (int q = 0; q < 4; ++q)
                Y[(size_t)(rg + q) * D_OUT + cg] = acc[m][n][q];
        }
    }
}

extern "C" void kernel_launch(void* const* d_in, const int* in_sizes, int n_in,
                              void* d_out, int out_size, void* d_ws, size_t ws_size,
                              hipStream_t stream) {
    const float* X = (const float*)d_in[0];   // [B*T, 4096] fp32
    const float* W = (const float*)d_in[1];   // [8, 512, 512] fp32
    float* Y = (float*)d_out;                 // [B*T, 4096] fp32
    const int M = in_sizes[0] / D_IN;         // 8192
    const int nwg = (M / BM) * (D_OUT / BN);  // 2048

    const size_t xb_bytes = (size_t)M * D_IN * sizeof(unsigned short);      // 64 MB
    const size_t wb_bytes = (size_t)D_OUT * D_IN * sizeof(unsigned short);  // 32 MB

    if (ws_size >= xb_bytes + wb_bytes) {
        unsigned short* Xb = (unsigned short*)d_ws;
        unsigned short* Wb = (unsigned short*)((char*)d_ws + xb_bytes);
        const int n8x = M * D_IN / 8;
        hipLaunchKernelGGL(conv_x, dim3(n8x / 256), dim3(256), 0, stream, X, Xb, n8x);
        hipLaunchKernelGGL(conv_w, dim3((D_OUT * D_IN / 8) / 256), dim3(256), 0, stream, W, Wb);
        hipLaunchKernelGGL(octo_gemm_bf16, dim3(nwg), dim3(256), 0, stream, Xb, Wb, Y, M);
    } else {
        hipLaunchKernelGGL(octo_gemm_f32, dim3(nwg), dim3(256), 0, stream, X, W, Y, M);
    }
}

// Round 3
// 263.549 us; speedup vs baseline: 2.2081x; 1.1941x over previous
//
#include <hip/hip_runtime.h>
#include <stdint.h>

typedef __attribute__((ext_vector_type(8))) short bf16x8;
typedef __attribute__((ext_vector_type(4))) float f32x4;

#define D_IN  4096
#define D_OUT 4096
#define KC 512   // per-component input dim
#define NC 512   // per-component output dim
#define NT 64    // K-tiles of BK=64

// SIGN_TABLE[i][j], row-major
__constant__ float c_sign[64] = {
 +1,-1,-1,-1,-1,-1,-1,-1,
 +1,+1,+1,-1,+1,-1,-1,+1,
 +1,-1,+1,+1,+1,+1,-1,-1,
 +1,+1,-1,+1,+1,-1,+1,-1,
 +1,-1,-1,-1,+1,+1,+1,+1,
 +1,+1,-1,+1,-1,+1,-1,+1,
 +1,+1,+1,-1,-1,+1,+1,-1,
 +1,-1,+1,+1,-1,-1,+1,+1,
};

__device__ inline unsigned int pack2bf16(float a, float b) {
    unsigned int ua = __builtin_bit_cast(unsigned int, a);
    unsigned int ub = __builtin_bit_cast(unsigned int, b);
    ua = (ua + 0x7FFFu + ((ua >> 16) & 1u)) >> 16;
    ub = (ub + 0x7FFFu + ((ub >> 16) & 1u)) >> 16;
    return ua | (ub << 16);
}

typedef __attribute__((address_space(1))) const unsigned int gas_u32;
typedef __attribute__((address_space(3))) unsigned int las_u32;
#define ASYNC16(g, l) __builtin_amdgcn_global_load_lds((gas_u32*)(g), (las_u32*)(l), 16, 0, 0)

// ---------- pre-conversion kernels ----------

__global__ __launch_bounds__(256)
void conv_x(const float* __restrict__ in, unsigned short* __restrict__ out, int n8) {
    int i = blockIdx.x * blockDim.x + threadIdx.x;
    if (i >= n8) return;
    const float4 a = ((const float4*)in)[(size_t)i * 2];
    const float4 b = ((const float4*)in)[(size_t)i * 2 + 1];
    uint4 o;
    o.x = pack2bf16(a.x, a.y); o.y = pack2bf16(a.z, a.w);
    o.z = pack2bf16(b.x, b.y); o.w = pack2bf16(b.z, b.w);
    ((uint4*)out)[i] = o;
}

// Wbig[i*512+n][j*512+k] = sign[i][j] * W[i^j][n][k], fp32 -> bf16
__global__ __launch_bounds__(256)
void conv_w(const float* __restrict__ W, unsigned short* __restrict__ out) {
    int gid = blockIdx.x * blockDim.x + threadIdx.x;   // 0 .. 4096*512-1
    int row = gid >> 9;
    int c8  = gid & 511;
    int i = row >> 9, n = row & 511;
    int j = c8 >> 6;
    int k = (c8 & 63) << 3;
    float sgn = c_sign[i * 8 + j];
    const float* src = W + ((((i ^ j) * NC + n) * KC) + k);
    float4 a = *(const float4*)(src);
    float4 b = *(const float4*)(src + 4);
    uint4 o;
    o.x = pack2bf16(a.x * sgn, a.y * sgn); o.y = pack2bf16(a.z * sgn, a.w * sgn);
    o.z = pack2bf16(b.x * sgn, b.y * sgn); o.w = pack2bf16(b.z * sgn, b.w * sgn);
    ((uint4*)out)[gid] = o;
}

// ---------- 256x256 8-phase bf16 GEMM: Y = Xb @ Wbig^T ----------

template<int P>
__device__ __forceinline__ void do_phase(
    const unsigned short* bufA, const unsigned short* bufB,
    f32x4 (&acc)[8][4], bf16x8 (&bfr)[4][2],
    const unsigned short* stg_g, unsigned short* stg_l,
    size_t goff0, size_t goff1, int loff0, int loff1,
    int lane, int wr, int wc)
{
    bf16x8 afr[2][2];
    #pragma unroll
    for (int q = 0; q < 2; ++q) {
        const int r = wr * 128 + (2 * P + q) * 16 + (lane & 15);
        #pragma unroll
        for (int kk = 0; kk < 2; ++kk) {
            const int ch = (kk * 4 + (lane >> 4)) ^ (r & 7);
            afr[q][kk] = *(const bf16x8*)((const char*)bufA + r * 128 + ch * 16);
        }
    }
    if (P == 0) {   // B fragments for the whole K-tile, kept in registers
        #pragma unroll
        for (int n = 0; n < 4; ++n) {
            const int r = wc * 64 + n * 16 + (lane & 15);
            #pragma unroll
            for (int kk = 0; kk < 2; ++kk) {
                const int ch = (kk * 4 + (lane >> 4)) ^ (r & 7);
                bfr[n][kk] = *(const bf16x8*)((const char*)bufB + r * 128 + ch * 16);
            }
        }
    }
    // stage one half-tile (2 x global_load_lds dwordx4)
    ASYNC16(stg_g + goff0, stg_l + loff0);
    ASYNC16(stg_g + goff1, stg_l + loff1);
    __builtin_amdgcn_s_barrier();
    asm volatile("s_waitcnt lgkmcnt(0)");
    __builtin_amdgcn_s_setprio(1);
    #pragma unroll
    for (int kk = 0; kk < 2; ++kk)
        #pragma unroll
        for (int q = 0; q < 2; ++q)
            #pragma unroll
            for (int n = 0; n < 4; ++n)
                acc[2 * P + q][n] = __builtin_amdgcn_mfma_f32_16x16x32_bf16(
                    afr[q][kk], bfr[n][kk], acc[2 * P + q][n], 0, 0, 0);
    __builtin_amdgcn_s_setprio(0);
}

#define ENDP do { __builtin_amdgcn_s_barrier(); asm volatile("" ::: "memory"); } while (0)

__global__ __launch_bounds__(512, 2)
void octo_gemm_8ph(const unsigned short* __restrict__ Xb,
                   const unsigned short* __restrict__ Wb,
                   float* __restrict__ Y, int M)
{
    // LDS: 2 K-tile double buffer; A(256x64) + B(256x64) bf16 each = 128 KiB.
    // Element (r,k): byte r*128 + ((chunk ^ (r&7))<<4) + low, chunk=(k*2)>>4;
    // achieved with linear LDS dest + inverse-swizzled GLOBAL source (rule #21).
    __shared__ __align__(16) unsigned short sm[65536];
    unsigned short* A0 = sm;
    unsigned short* A1 = sm + 16384;
    unsigned short* B0 = sm + 32768;
    unsigned short* B1 = sm + 49152;

    const int tid  = threadIdx.x;
    const int lane = tid & 63;
    const int wave = tid >> 6;
    const int wr   = wave >> 2;      // 2x4 wave grid; wave owns 128x64 output
    const int wc   = wave & 3;

    const int nbn = D_OUT / 256;                // 16
    const int nwg = (M / 256) * nbn;            // 512
    int bid = blockIdx.x;
    int cpx = nwg >> 3;                         // bijective XCD swizzle (nwg%8==0)
    int wg  = (bid & 7) * cpx + (bid >> 3);
    const int bm = wg / nbn, bn = wg % nbn;
    const int row0 = bm * 256, col0 = bn * 256;

    // staging geometry: half-tile = 128 rows x 64 cols bf16; 2 loads/thread
    const int srow  = tid >> 3;                 // 0..63
    const int sch   = tid & 7;                  // 16B chunk
    const size_t goff0 = (size_t)srow * D_IN + (size_t)((sch ^ (srow & 7)) * 8);
    const size_t goff1 = goff0 + (size_t)64 * D_IN;   // (64+srow)&7 == srow&7
    const int loff0 = tid * 8;                  // ushort elems; = lane*16B per wave
    const int loff1 = loff0 + 4096;

    const unsigned short* gX = Xb + (size_t)row0 * D_IN;
    const unsigned short* gW = Wb + (size_t)col0 * D_IN;

    f32x4 acc[8][4];
    #pragma unroll
    for (int m = 0; m < 8; ++m)
        #pragma unroll
        for (int n = 0; n < 4; ++n)
            acc[m][n] = (f32x4){0.f, 0.f, 0.f, 0.f};

    // ---- prologue: tile0 A+B -> buf0, tile1 B -> buf1.B (6 half-tiles) ----
    ASYNC16(gX + goff0, A0 + loff0);              ASYNC16(gX + goff1, A0 + loff1);
    ASYNC16(gX + 128 * D_IN + goff0, A0 + 8192 + loff0);
    ASYNC16(gX + 128 * D_IN + goff1, A0 + 8192 + loff1);
    ASYNC16(gW + goff0, B0 + loff0);              ASYNC16(gW + goff1, B0 + loff1);
    ASYNC16(gW + 128 * D_IN + goff0, B0 + 8192 + loff0);
    ASYNC16(gW + 128 * D_IN + goff1, B0 + 8192 + loff1);
    ASYNC16(gW + 64 + goff0, B1 + loff0);         ASYNC16(gW + 64 + goff1, B1 + loff1);
    ASYNC16(gW + 64 + 128 * D_IN + goff0, B1 + 8192 + loff0);
    ASYNC16(gW + 64 + 128 * D_IN + goff1, B1 + 8192 + loff1);
    asm volatile("s_waitcnt vmcnt(4)");           // tile0's 8 loads landed
    ENDP;

    bf16x8 bfr[4][2];
    for (int i = 0; i < NT / 2; ++i) {
        const int u = 2 * i;
        // tail iterations stage wrapped tiles (&63): keeps vmcnt counts uniform;
        // wrapped data lands in regions that are never read again (race-free).
        const unsigned short* gA1t = gX + ((u + 1) & (NT - 1)) * 64;
        const unsigned short* gA2t = gX + ((u + 2) & (NT - 1)) * 64;
        const unsigned short* gB2t = gW + ((u + 2) & (NT - 1)) * 64;
        const unsigned short* gB3t = gW + ((u + 3) & (NT - 1)) * 64;

        // phases 0-3: compute tile u from buf0
        do_phase<0>(A0, B0, acc, bfr, gA1t,            A1,        goff0, goff1, loff0, loff1, lane, wr, wc);
        ENDP;
        do_phase<1>(A0, B0, acc, bfr, gA1t + 128*D_IN, A1 + 8192, goff0, goff1, loff0, loff1, lane, wr, wc);
        ENDP;
        do_phase<2>(A0, B0, acc, bfr, gB2t,            B0,        goff0, goff1, loff0, loff1, lane, wr, wc);
        ENDP;
        do_phase<3>(A0, B0, acc, bfr, gB2t + 128*D_IN, B0 + 8192, goff0, goff1, loff0, loff1, lane, wr, wc);
        asm volatile("s_waitcnt vmcnt(4)");       // tile u+1 fully landed
        ENDP;
        // phases 4-7: compute tile u+1 from buf1
        do_phase<0>(A1, B1, acc, bfr, gA2t,            A0,        goff0, goff1, loff0, loff1, lane, wr, wc);
        ENDP;
        do_phase<1>(A1, B1, acc, bfr, gA2t + 128*D_IN, A0 + 8192, goff0, goff1, loff0, loff1, lane, wr, wc);
        ENDP;
        do_phase<2>(A1, B1, acc, bfr, gB3t,            B1,        goff0, goff1, loff0, loff1, lane, wr, wc);
        ENDP;
        do_phase<3>(A1, B1, acc, bfr, gB3t + 128*D_IN, B1 + 8192, goff0, goff1, loff0, loff1, lane, wr, wc);
        asm volatile("s_waitcnt vmcnt(4)");       // tile u+2 fully landed
        ENDP;
    }

    // epilogue: C/D layout col=lane&15, row=(lane>>4)*4+reg  [m89/m91]
    const int rl = (lane >> 4) << 2;
    const int cl = lane & 15;
    #pragma unroll
    for (int m = 0; m < 8; ++m) {
        const int rg = row0 + wr * 128 + m * 16 + rl;
        #pragma unroll
        for (int n = 0; n < 4; ++n) {
            const int cg = col0 + wc * 64 + n * 16 + cl;
            #pragma unroll
            for (int q = 0; q < 4; ++q)
                Y[(size_t)(rg + q) * D_OUT + cg] = acc[m][n][q];
        }
    }
}

// ---------- fallback: fused fp32-staging kernel (no workspace) ----------

#define BM 128
#define BN 128
#define BK 64

__global__ __launch_bounds__(256)
void octo_gemm_f32(const float* __restrict__ X, const float* __restrict__ W,
                   float* __restrict__ Y, int M)
{
    __shared__ __align__(16) unsigned short As[BM * BK];
    __shared__ __align__(16) unsigned short Bs[BN * BK];

    const int tid  = threadIdx.x;
    const int lane = tid & 63;
    const int wave = tid >> 6;
    const int wr   = wave >> 1;
    const int wc   = wave & 1;

    const int nbn = D_OUT / BN;
    const int nwg = (M / BM) * nbn;
    int bid = blockIdx.x;
    int wg  = bid;
    if ((nwg & 7) == 0) {
        int cpx = nwg >> 3;
        wg = (bid & 7) * cpx + (bid >> 3);
    }
    const int bm = wg / nbn, bn = wg % nbn;
    const int row0  = bm * BM;
    const int col0  = bn * BN;
    const int icomp = col0 >> 9;
    const int noff  = col0 & (NC - 1);

    const int srow = tid >> 4;
    const int scol = (tid & 15) << 2;

    f32x4 acc[4][4];
    #pragma unroll
    for (int m = 0; m < 4; ++m)
        #pragma unroll
        for (int n = 0; n < 4; ++n)
            acc[m][n] = (f32x4){0.f, 0.f, 0.f, 0.f};

    char* AsB = (char*)As;
    char* BsB = (char*)Bs;
    const int byteC = scol << 1;

    for (int step = 0; step < NT; ++step) {
        const int k0 = step * BK;
        const int j  = k0 >> 9;
        const int kc = k0 & (KC - 1);
        const float sgn = c_sign[icomp * 8 + j];
        const int   w   = icomp ^ j;
        const float* Wp = W + (((size_t)w * NC + noff) * KC + kc);
        const float* Xp = X + ((size_t)row0 * D_IN + k0);

        __syncthreads();
        #pragma unroll
        for (int p = 0; p < 8; ++p) {
            const int r  = p * 16 + srow;
            const int sb = r * 128 + ((((byteC >> 4) ^ (r & 7)) << 4)) + (byteC & 8);
            const float4 va = *(const float4*)(&Xp[(size_t)r * D_IN + scol]);
            *(uint2*)(AsB + sb) = make_uint2(pack2bf16(va.x, va.y),
                                             pack2bf16(va.z, va.w));
            const float4 vb = *(const float4*)(&Wp[(size_t)r * KC + scol]);
            *(uint2*)(BsB + sb) = make_uint2(pack2bf16(vb.x * sgn, vb.y * sgn),
                                             pack2bf16(vb.z * sgn, vb.w * sgn));
        }
        __syncthreads();

        #pragma unroll
        for (int kk = 0; kk < 2; ++kk) {
            bf16x8 af[4], bf[4];
            #pragma unroll
            for (int m = 0; m < 4; ++m) {
                const int r = wr * 64 + m * 16 + (lane & 15);
                const int chunk = (kk * 4 + (lane >> 4)) ^ (r & 7);
                af[m] = *(const bf16x8*)(AsB + r * 128 + (chunk << 4));
            }
            #pragma unroll
            for (int n = 0; n < 4; ++n) {
                const int r = wc * 64 + n * 16 + (lane & 15);
                const int chunk = (kk * 4 + (lane >> 4)) ^ (r & 7);
                bf[n] = *(const bf16x8*)(BsB + r * 128 + (chunk << 4));
            }
            #pragma unroll
            for (int m = 0; m < 4; ++m)
                #pragma unroll
                for (int n = 0; n < 4; ++n)
                    acc[m][n] = __builtin_amdgcn_mfma_f32_16x16x32_bf16(
                        af[m], bf[n], acc[m][n], 0, 0, 0);
        }
    }

    const int rl = (lane >> 4) << 2;
    const int cl = lane & 15;
    #pragma unroll
    for (int m = 0; m < 4; ++m) {
        const int rg = row0 + wr * 64 + m * 16 + rl;
        #pragma unroll
        for (int n = 0; n < 4; ++n) {
            const int cg = col0 + wc * 64 + n * 16 + cl;
            #pragma unroll
            for (int q = 0; q < 4; ++q)
                Y[(size_t)(rg + q) * D_OUT + cg] = acc[m][n][q];
        }
    }
}

extern "C" void kernel_launch(void* const* d_in, const int* in_sizes, int n_in,
                              void* d_out, int out_size, void* d_ws, size_t ws_size,
                              hipStream_t stream) {
    const float* X = (const float*)d_in[0];   // [B*T, 4096] fp32
    const float* W = (const float*)d_in[1];   // [8, 512, 512] fp32
    float* Y = (float*)d_out;                 // [B*T, 4096] fp32
    const int M = in_sizes[0] / D_IN;         // 8192

    const size_t xb_bytes = (size_t)M * D_IN * sizeof(unsigned short);      // 64 MB
    const size_t wb_bytes = (size_t)D_OUT * D_IN * sizeof(unsigned short);  // 32 MB

    if (ws_size >= xb_bytes + wb_bytes && (M % 256) == 0) {
        unsigned short* Xb = (unsigned short*)d_ws;
        unsigned short* Wb = (unsigned short*)((char*)d_ws + xb_bytes);
        const int n8x = M * D_IN / 8;
        hipLaunchKernelGGL(conv_x, dim3(n8x / 256), dim3(256), 0, stream, X, Xb, n8x);
        hipLaunchKernelGGL(conv_w, dim3((D_OUT * D_IN / 8) / 256), dim3(256), 0, stream, W, Wb);
        const int nwg = (M / 256) * (D_OUT / 256);   // 512
        hipLaunchKernelGGL(octo_gemm_8ph, dim3(nwg), dim3(512), 0, stream, Xb, Wb, Y, M);
    } else {
        const int nwg = (M / BM) * (D_OUT / BN);
        hipLaunchKernelGGL(octo_gemm_f32, dim3(nwg), dim3(256), 0, stream, X, W, Y, M);
    }
}